// Round 3
// baseline (1132.725 us; speedup 1.0000x reference)
//
#include <hip/hip_runtime.h>
#include <hip/hip_fp16.h>

#define N_NODES 50000
#define N_EDGES 1600000
#define FEAT    1536
#define HID     200
#define HIDP    208      // padded to 13*16 for MFMA-N
#define HID2    416      // both branches, padded
#define KDIM    768
#define NCHUNK  13       // 416 / 32
#define SCAN_B  196      // 196*256 = 50176 >= 50000

typedef _Float16 half8 __attribute__((ext_vector_type(8)));
typedef _Float16 half4 __attribute__((ext_vector_type(4)));
typedef float   float4v __attribute__((ext_vector_type(4)));

// ---------------- prep: W1 -> fp16 transposed+padded, b1/W2 combined+padded ----
__global__ void prep_kernel(const float* __restrict__ W1a, const float* __restrict__ b1a,
                            const float* __restrict__ W2a,
                            const float* __restrict__ W1b, const float* __restrict__ b1b,
                            const float* __restrict__ W2b,
                            _Float16* __restrict__ Wht, float* __restrict__ b1comb,
                            float* __restrict__ W2comb) {
  int i = blockIdx.x * 256 + threadIdx.x;
  if (i < 2 * HIDP * KDIM) {
    int br = i / (HIDP * KDIM);
    int r  = i % (HIDP * KDIM);
    int n = r / KDIM, k = r % KDIM;
    const float* W = br ? W1b : W1a;             // (768,200) row-major
    Wht[i] = (n < HID) ? (_Float16)W[k * HID + n] : (_Float16)0.0f;  // Wht[br][n][k]
  }
  if (i < HID2) {
    int br = i / HIDP, c = i % HIDP;
    const float* b  = br ? b1b : b1a;
    const float* W2 = br ? W2b : W2a;            // (200,2) row-major
    bool ok = (c < HID);
    b1comb[i]       = ok ? b[c]        : 0.0f;
    W2comb[2*i + 0] = ok ? W2[c*2 + 0] : 0.0f;
    W2comb[2*i + 1] = ok ? W2[c*2 + 1] : 0.0f;
  }
}

// ---------------- CSR build: histogram ----------------
__global__ void hist_kernel(const int* __restrict__ dst, int* __restrict__ cnt) {
  int i = blockIdx.x * 256 + threadIdx.x;
  if (i < N_EDGES) atomicAdd(&cnt[dst[i]], 1);
}

// ---------------- CSR build: 3-stage coalesced exclusive scan ----------------
__global__ void scanA_kernel(const int* __restrict__ cnt, int* __restrict__ bsum) {
  __shared__ int s[256];
  int t = threadIdx.x, i = blockIdx.x * 256 + t;
  s[t] = (i < N_NODES) ? cnt[i] : 0;
  __syncthreads();
  for (int off = 128; off; off >>= 1) {
    if (t < off) s[t] += s[t + off];
    __syncthreads();
  }
  if (t == 0) bsum[blockIdx.x] = s[0];
}
__global__ void scanB_kernel(const int* __restrict__ bsum, int* __restrict__ boff,
                             int* __restrict__ row_ptr) {
  __shared__ int s[256];
  int t = threadIdx.x;
  int v = (t < SCAN_B) ? bsum[t] : 0;
  s[t] = v;
  __syncthreads();
  for (int off = 1; off < 256; off <<= 1) {
    int a = (t >= off) ? s[t - off] : 0;
    __syncthreads();
    s[t] += a;
    __syncthreads();
  }
  boff[t] = s[t] - v;                      // exclusive block offset
  if (t == SCAN_B - 1) row_ptr[N_NODES] = s[t];   // grand total
}
__global__ void scanC_kernel(const int* __restrict__ cnt, const int* __restrict__ boff,
                             int* __restrict__ row_ptr) {
  __shared__ int s[256];
  int t = threadIdx.x, i = blockIdx.x * 256 + t;
  int v = (i < N_NODES) ? cnt[i] : 0;
  s[t] = v;
  __syncthreads();
  for (int off = 1; off < 256; off <<= 1) {
    int a = (t >= off) ? s[t - off] : 0;
    __syncthreads();
    s[t] += a;
    __syncthreads();
  }
  if (i < N_NODES) row_ptr[i] = boff[blockIdx.x] + s[t] - v;   // exclusive
}

// ---------------- CSR build: permute edges into dst-sorted order ----------------
__global__ void permute_kernel(const int* __restrict__ src, const int* __restrict__ dst,
                               const float* __restrict__ w, const int* __restrict__ row_ptr,
                               int* __restrict__ cnt2, int2* __restrict__ ssw) {
  int i = blockIdx.x * 256 + threadIdx.x;
  if (i < N_EDGES) {
    int d = dst[i];
    int pos = row_ptr[d] + atomicAdd(&cnt2[d], 1);
    ssw[pos] = make_int2(src[i], __float_as_int(w[i]));
  }
}

// ---------------- GEMM1: hpre_c[chunk][node][32] = fp16( x_half @ W1 ) ----------------
// grid (391, 2), block 256. Tile 128(M) x 208(N) x 32(K). Wave-tile 32x208.
__global__ __launch_bounds__(256, 2) void gemm1_kernel(const float* __restrict__ x,
    const _Float16* __restrict__ Wht, _Float16* __restrict__ hpre_c) {
  const int m0 = blockIdx.x * 128;
  const int br = blockIdx.y;
  const int tid = threadIdx.x;
  const int wave = tid >> 6, lane = tid & 63;
  __shared__ _Float16 Alds[128][40];             // +8 halfs pad (bank spread)
  __shared__ _Float16 Blds[HIDP][40];
  const _Float16* Wb = Wht + (size_t)br * HIDP * KDIM;
  float4v acc[2][13];
#pragma unroll
  for (int mt = 0; mt < 2; ++mt)
#pragma unroll
    for (int nt = 0; nt < 13; ++nt) acc[mt][nt] = (float4v){0.f, 0.f, 0.f, 0.f};

  const int mlo = lane & 15, kq = (lane >> 4) * 8;

  for (int k0 = 0; k0 < KDIM; k0 += 32) {
    __syncthreads();
    // stage A: 128 rows x 32 k (fp32 -> fp16)
#pragma unroll
    for (int p = 0; p < 4; ++p) {
      int idx = tid + p * 256;                   // 0..1023 = 128 rows * 8 float4
      int row = idx >> 3, c4 = idx & 7;
      int grow = m0 + row; if (grow > N_NODES - 1) grow = N_NODES - 1;
      const float4v xv = *(const float4v*)(x + (size_t)grow * FEAT + br * KDIM + k0 + c4 * 4);
      half4 hv = {(_Float16)xv[0], (_Float16)xv[1], (_Float16)xv[2], (_Float16)xv[3]};
      *(half4*)&Alds[row][c4 * 4] = hv;
    }
    // stage B: 208 n-rows x 32 k (already fp16, [n][k] layout)
    for (int idx = tid; idx < HIDP * 4; idx += 256) {
      int n = idx >> 2, c = idx & 3;
      *(half8*)&Blds[n][c * 8] = *(const half8*)(Wb + n * KDIM + k0 + c * 8);
    }
    __syncthreads();
    half8 a0 = *(half8*)&Alds[wave * 32 + mlo][kq];
    half8 a1 = *(half8*)&Alds[wave * 32 + 16 + mlo][kq];
#pragma unroll
    for (int nt = 0; nt < 13; ++nt) {
      half8 b = *(half8*)&Blds[nt * 16 + mlo][kq];
      acc[0][nt] = __builtin_amdgcn_mfma_f32_16x16x32_f16(a0, b, acc[0][nt], 0, 0, 0);
      acc[1][nt] = __builtin_amdgcn_mfma_f32_16x16x32_f16(a1, b, acc[1][nt], 0, 0, 0);
    }
  }
  // epilogue: D-layout n = lane&15, m = (lane>>4)*4 + r ; store chunk-major
  const int nlo = lane & 15, mq = (lane >> 4) * 4;
#pragma unroll
  for (int mt = 0; mt < 2; ++mt)
#pragma unroll
    for (int nt = 0; nt < 13; ++nt) {
      int col = br * HIDP + nt * 16 + nlo;       // 0..415
      int c = col >> 5, off = col & 31;
#pragma unroll
      for (int r = 0; r < 4; ++r) {
        int row = m0 + wave * 32 + mt * 16 + mq + r;
        if (row < N_NODES)
          hpre_c[((size_t)c * N_NODES + row) * 32 + off] = (_Float16)acc[mt][nt][r];
      }
    }
}

// ---------------- agg1c: chunked CSR gather-reduce + bias + relu + fused W2 dot -----
// grid (12500, 13), block 256 = 4 waves; wave handles one dst node for one chunk.
// lane = esub*4 + c4 : 16 edges in flight, each edge's 64-B chunk read by 4 lanes.
__global__ __launch_bounds__(256) void agg1c_kernel(const int2* __restrict__ ssw,
    const int* __restrict__ row_ptr, const _Float16* __restrict__ hpre_c,
    const float* __restrict__ b1comb, const float* __restrict__ W2comb,
    float* __restrict__ qtab) {
  const int chunk = blockIdx.y;
  const int d = blockIdx.x * 4 + (threadIdx.x >> 6);
  const int lane = threadIdx.x & 63;
  const int esub = lane >> 2, c4 = lane & 3;
  const int e0 = row_ptr[d], e1 = row_ptr[d + 1];
  const _Float16* tab = hpre_c + (size_t)chunk * N_NODES * 32 + c4 * 8;
  float acc[8];
#pragma unroll
  for (int j = 0; j < 8; ++j) acc[j] = 0.f;
  for (int e = e0 + esub; e < e1; e += 16) {
    int2 s = ssw[e];
    float w = __int_as_float(s.y);
    half8 h = *(const half8*)(tab + (size_t)s.x * 32);
#pragma unroll
    for (int j = 0; j < 8; ++j) acc[j] += w * (float)h[j];
  }
  // sum over the 16 edge-groups (lane stride 4)
#pragma unroll
  for (int off = 4; off < 64; off <<= 1)
#pragma unroll
    for (int j = 0; j < 8; ++j) acc[j] += __shfl_xor(acc[j], off);
  // fused bias + relu + layer-2 dot for this lane's 8 features
  float qa0 = 0.f, qa1 = 0.f, qb0 = 0.f, qb1 = 0.f;
  const int base = chunk * 32 + c4 * 8;
#pragma unroll
  for (int j = 0; j < 8; ++j) {
    int col = base + j;
    float h = fmaxf(acc[j] + b1comb[col], 0.f);
    float w20 = W2comb[2 * col + 0], w21 = W2comb[2 * col + 1];
    bool isA = col < HIDP;
    qa0 += isA ? h * w20 : 0.f;
    qa1 += isA ? h * w21 : 0.f;
    qb0 += isA ? 0.f : h * w20;
    qb1 += isA ? 0.f : h * w21;
  }
#pragma unroll
  for (int off = 1; off < 4; off <<= 1) {
    qa0 += __shfl_xor(qa0, off);
    qa1 += __shfl_xor(qa1, off);
    qb0 += __shfl_xor(qb0, off);
    qb1 += __shfl_xor(qb1, off);
  }
  if (lane == 0) {
    atomicAdd(&qtab[d * 4 + 0], qa0);
    atomicAdd(&qtab[d * 4 + 1], qa1);
    atomicAdd(&qtab[d * 4 + 2], qb0);
    atomicAdd(&qtab[d * 4 + 3], qb1);
  }
}

// ---------------- agg2: layer-2 segment_sum + softmax + vote ----------------
__global__ __launch_bounds__(256) void agg2_kernel(const int2* __restrict__ ssw,
    const int* __restrict__ row_ptr, const float* __restrict__ qtab,
    const float* __restrict__ b2a, const float* __restrict__ b2b,
    float* __restrict__ out) {
  const int d = blockIdx.x * 4 + (threadIdx.x >> 6);
  const int lane = threadIdx.x & 63;
  const int e0 = row_ptr[d], e1 = row_ptr[d + 1];
  float a0 = 0.f, a1 = 0.f, a2 = 0.f, a3 = 0.f;
  for (int e = e0 + lane; e < e1; e += 64) {
    int2 sw = ssw[e];
    float w = __int_as_float(sw.y);
    const float4v q = *(const float4v*)(qtab + (size_t)sw.x * 4);
    a0 += w * q[0]; a1 += w * q[1]; a2 += w * q[2]; a3 += w * q[3];
  }
#pragma unroll
  for (int off = 32; off > 0; off >>= 1) {
    a0 += __shfl_xor(a0, off);
    a1 += __shfl_xor(a1, off);
    a2 += __shfl_xor(a2, off);
    a3 += __shfl_xor(a3, off);
  }
  if (lane == 0) {
    float za0 = a0 + b2a[0], za1 = a1 + b2a[1];
    float zb0 = a2 + b2b[0], zb1 = a3 + b2b[1];
    float m1 = fmaxf(za0, za1);
    float ea0 = __expf(za0 - m1), ea1 = __expf(za1 - m1);
    float p10 = ea0 / (ea0 + ea1), p11 = ea1 / (ea0 + ea1);
    float m2 = fmaxf(zb0, zb1);
    float eb0 = __expf(zb0 - m2), eb1 = __expf(zb1 - m2);
    float p20 = eb0 / (eb0 + eb1), p21 = eb1 / (eb0 + eb1);
    float v0 = fmaxf(p10, p20), v1 = fmaxf(p11, p21);
    float s = v0 + v1;
    out[d * 2 + 0] = v0 / s;
    out[d * 2 + 1] = v1 / s;
  }
}

extern "C" void kernel_launch(void* const* d_in, const int* in_sizes, int n_in,
                              void* d_out, int out_size, void* d_ws, size_t ws_size,
                              hipStream_t stream) {
  const float* x        = (const float*)d_in[0];
  const int*   edge_src = (const int*)d_in[1];
  const int*   edge_dst = (const int*)d_in[2];
  const float* edge_w   = (const float*)d_in[3];
  const float* W1a = (const float*)d_in[4];
  const float* b1a = (const float*)d_in[5];
  const float* W2a = (const float*)d_in[6];
  const float* b2a = (const float*)d_in[7];
  const float* W1b = (const float*)d_in[8];
  const float* b1b = (const float*)d_in[9];
  const float* W2b = (const float*)d_in[10];
  const float* b2b = (const float*)d_in[11];
  float* out = (float*)d_out;

  char* ws = (char*)d_ws;
  size_t off = 0;
  auto alloc = [&](size_t bytes) -> void* {
    void* p = ws + off;
    off = (off + bytes + 255) & ~(size_t)255;
    return p;
  };
  _Float16* Wht  = (_Float16*)alloc((size_t)2 * HIDP * KDIM * sizeof(_Float16)); // 639 KB
  float* b1comb  = (float*)alloc(HID2 * sizeof(float));
  float* W2comb  = (float*)alloc(HID2 * 2 * sizeof(float));
  int* row_ptr   = (int*)alloc((N_NODES + 1) * sizeof(int));
  int* cnt       = (int*)alloc(N_NODES * sizeof(int));
  int* cnt2      = (int*)alloc(N_NODES * sizeof(int));
  int* bsum      = (int*)alloc(SCAN_B * sizeof(int));
  int* boff      = (int*)alloc(256 * sizeof(int));
  int2* ssw      = (int2*)alloc((size_t)N_EDGES * sizeof(int2));                 // 12.8 MB
  float* qtab    = (float*)alloc((size_t)N_NODES * 4 * sizeof(float));           // 800 KB
  _Float16* hpre = (_Float16*)alloc((size_t)N_NODES * HID2 * sizeof(_Float16));  // 41.6 MB, chunk-major
  (void)ws_size; (void)in_sizes; (void)n_in; (void)out_size;

  (void)hipMemsetAsync(cnt,  0, N_NODES * sizeof(int), stream);
  (void)hipMemsetAsync(cnt2, 0, N_NODES * sizeof(int), stream);
  (void)hipMemsetAsync(qtab, 0, N_NODES * 4 * sizeof(float), stream);

  prep_kernel<<<dim3((2 * HIDP * KDIM + 255) / 256), dim3(256), 0, stream>>>(
      W1a, b1a, W2a, W1b, b1b, W2b, Wht, b1comb, W2comb);
  hist_kernel<<<dim3((N_EDGES + 255) / 256), dim3(256), 0, stream>>>(edge_dst, cnt);
  scanA_kernel<<<dim3(SCAN_B), dim3(256), 0, stream>>>(cnt, bsum);
  scanB_kernel<<<dim3(1), dim3(256), 0, stream>>>(bsum, boff, row_ptr);
  scanC_kernel<<<dim3(SCAN_B), dim3(256), 0, stream>>>(cnt, boff, row_ptr);
  permute_kernel<<<dim3((N_EDGES + 255) / 256), dim3(256), 0, stream>>>(
      edge_src, edge_dst, edge_w, row_ptr, cnt2, ssw);
  gemm1_kernel<<<dim3((N_NODES + 127) / 128, 2), dim3(256), 0, stream>>>(x, Wht, hpre);
  agg1c_kernel<<<dim3(N_NODES / 4, NCHUNK), dim3(256), 0, stream>>>(
      ssw, row_ptr, hpre, b1comb, W2comb, qtab);
  agg2_kernel<<<dim3(N_NODES / 4), dim3(256), 0, stream>>>(ssw, row_ptr, qtab, b2a, b2b, out);
}

// Round 4
// 860.945 us; speedup vs baseline: 1.3157x; 1.3157x over previous
//
#include <hip/hip_runtime.h>
#include <hip/hip_fp16.h>

#define N_NODES 50000
#define N_EDGES 1600000
#define FEAT    1536
#define HID     200
#define HIDP    208      // padded to 13*16 for MFMA-N
#define HID2    416      // both branches, padded
#define KDIM    768
#define NSTRIPE 16       // src stripes for L2 sweep locality
#define STRW    3200     // stripe width in nodes (3200*16 = 51200 >= 50000)
#define NKEYS   (N_NODES * NSTRIPE)   // 800000 buckets
#define L0B     3125     // 800000 / 256 exactly
#define L1B     13       // ceil(3125/256)

typedef _Float16 half8 __attribute__((ext_vector_type(8)));
typedef _Float16 half4 __attribute__((ext_vector_type(4)));
typedef float   float4v __attribute__((ext_vector_type(4)));

// ---------------- prep: W1 -> fp16 transposed+padded, b1/W2 combined+padded ----
__global__ void prep_kernel(const float* __restrict__ W1a, const float* __restrict__ b1a,
                            const float* __restrict__ W2a,
                            const float* __restrict__ W1b, const float* __restrict__ b1b,
                            const float* __restrict__ W2b,
                            _Float16* __restrict__ Wht, float* __restrict__ b1comb,
                            float* __restrict__ W2comb) {
  int i = blockIdx.x * 256 + threadIdx.x;
  if (i < 2 * HIDP * KDIM) {
    int br = i / (HIDP * KDIM);
    int r  = i % (HIDP * KDIM);
    int n = r / KDIM, k = r % KDIM;
    const float* W = br ? W1b : W1a;             // (768,200) row-major
    Wht[i] = (n < HID) ? (_Float16)W[k * HID + n] : (_Float16)0.0f;  // Wht[br][n][k]
  }
  if (i < HID2) {
    int br = i / HIDP, c = i % HIDP;
    const float* b  = br ? b1b : b1a;
    const float* W2 = br ? W2b : W2a;            // (200,2) row-major
    bool ok = (c < HID);
    b1comb[i]       = ok ? b[c]        : 0.0f;
    W2comb[2*i + 0] = ok ? W2[c*2 + 0] : 0.0f;
    W2comb[2*i + 1] = ok ? W2[c*2 + 1] : 0.0f;
  }
}

// ---------------- CSR build: histogram over (dst, src-stripe) buckets ----------------
__global__ void hist_kernel(const int* __restrict__ src, const int* __restrict__ dst,
                            int* __restrict__ cnt) {
  int i = blockIdx.x * 256 + threadIdx.x;
  if (i < N_EDGES) {
    int key = dst[i] * NSTRIPE + src[i] / STRW;
    atomicAdd(&cnt[key], 1);
  }
}

// ---------------- 3-level exclusive scan over 800000 bucket counts ----------------
__global__ void scanA_kernel(const int* __restrict__ cnt, int* __restrict__ bsum) {
  __shared__ int s[256];
  int t = threadIdx.x;
  s[t] = cnt[blockIdx.x * 256 + t];              // NKEYS = 3125*256 exactly
  __syncthreads();
  for (int off = 128; off; off >>= 1) {
    if (t < off) s[t] += s[t + off];
    __syncthreads();
  }
  if (t == 0) bsum[blockIdx.x] = s[0];
}
__global__ void scanM1_kernel(const int* __restrict__ bsum, int* __restrict__ bsumB) {
  __shared__ int s[256];
  int t = threadIdx.x, i = blockIdx.x * 256 + t;
  s[t] = (i < L0B) ? bsum[i] : 0;
  __syncthreads();
  for (int off = 128; off; off >>= 1) {
    if (t < off) s[t] += s[t + off];
    __syncthreads();
  }
  if (t == 0) bsumB[blockIdx.x] = s[0];
}
__global__ void scanTop_kernel(const int* __restrict__ bsumB, int* __restrict__ boff2,
                               int* __restrict__ bptr) {
  if (threadIdx.x == 0) {
    int run = 0;
    for (int j = 0; j < L1B; ++j) { boff2[j] = run; run += bsumB[j]; }
    bptr[NKEYS] = run;                            // = N_EDGES
  }
}
__global__ void scanMid_kernel(const int* __restrict__ bsum, const int* __restrict__ boff2,
                               int* __restrict__ boff1) {
  __shared__ int s[256];
  int t = threadIdx.x, i = blockIdx.x * 256 + t;
  int v = (i < L0B) ? bsum[i] : 0;
  s[t] = v;
  __syncthreads();
  for (int off = 1; off < 256; off <<= 1) {
    int a = (t >= off) ? s[t - off] : 0;
    __syncthreads();
    s[t] += a;
    __syncthreads();
  }
  if (i < L0B) boff1[i] = boff2[blockIdx.x] + s[t] - v;   // exclusive
}
__global__ void scanLow_kernel(const int* __restrict__ cnt, const int* __restrict__ boff1,
                               int* __restrict__ bptr) {
  __shared__ int s[256];
  int t = threadIdx.x, i = blockIdx.x * 256 + t;
  int v = cnt[i];
  s[t] = v;
  __syncthreads();
  for (int off = 1; off < 256; off <<= 1) {
    int a = (t >= off) ? s[t - off] : 0;
    __syncthreads();
    s[t] += a;
    __syncthreads();
  }
  bptr[i] = boff1[blockIdx.x] + s[t] - v;                 // exclusive
}

// ---------------- permute edges into (dst, src-stripe) sorted order ----------------
__global__ void permute_kernel(const int* __restrict__ src, const int* __restrict__ dst,
                               const float* __restrict__ w, const int* __restrict__ bptr,
                               int* __restrict__ cnt2, int2* __restrict__ ssw) {
  int i = blockIdx.x * 256 + threadIdx.x;
  if (i < N_EDGES) {
    int key = dst[i] * NSTRIPE + src[i] / STRW;
    int pos = bptr[key] + atomicAdd(&cnt2[key], 1);
    ssw[pos] = make_int2(src[i], __float_as_int(w[i]));
  }
}

// ---------------- GEMM1: hpre[node][416] = fp16( x_half @ W1 ), both branches -------
// grid (391, 2), block 256. Tile 128(M) x 208(N) x 32(K). Wave-tile 32x208.
__global__ __launch_bounds__(256, 2) void gemm1_kernel(const float* __restrict__ x,
    const _Float16* __restrict__ Wht, _Float16* __restrict__ hpre) {
  const int m0 = blockIdx.x * 128;
  const int br = blockIdx.y;
  const int tid = threadIdx.x;
  const int wave = tid >> 6, lane = tid & 63;
  __shared__ _Float16 Alds[128][40];             // +8 halfs pad (bank spread)
  __shared__ _Float16 Blds[HIDP][40];
  const _Float16* Wb = Wht + (size_t)br * HIDP * KDIM;
  float4v acc[2][13];
#pragma unroll
  for (int mt = 0; mt < 2; ++mt)
#pragma unroll
    for (int nt = 0; nt < 13; ++nt) acc[mt][nt] = (float4v){0.f, 0.f, 0.f, 0.f};

  const int mlo = lane & 15, kq = (lane >> 4) * 8;

  for (int k0 = 0; k0 < KDIM; k0 += 32) {
    __syncthreads();
    // stage A: 128 rows x 32 k (fp32 -> fp16)
#pragma unroll
    for (int p = 0; p < 4; ++p) {
      int idx = tid + p * 256;                   // 0..1023 = 128 rows * 8 float4
      int row = idx >> 3, c4 = idx & 7;
      int grow = m0 + row; if (grow > N_NODES - 1) grow = N_NODES - 1;
      const float4v xv = *(const float4v*)(x + (size_t)grow * FEAT + br * KDIM + k0 + c4 * 4);
      half4 hv = {(_Float16)xv[0], (_Float16)xv[1], (_Float16)xv[2], (_Float16)xv[3]};
      *(half4*)&Alds[row][c4 * 4] = hv;
    }
    // stage B: 208 n-rows x 32 k (already fp16, [n][k] layout)
    for (int idx = tid; idx < HIDP * 4; idx += 256) {
      int n = idx >> 2, c = idx & 3;
      *(half8*)&Blds[n][c * 8] = *(const half8*)(Wb + n * KDIM + k0 + c * 8);
    }
    __syncthreads();
    half8 a0 = *(half8*)&Alds[wave * 32 + mlo][kq];
    half8 a1 = *(half8*)&Alds[wave * 32 + 16 + mlo][kq];
#pragma unroll
    for (int nt = 0; nt < 13; ++nt) {
      half8 b = *(half8*)&Blds[nt * 16 + mlo][kq];
      acc[0][nt] = __builtin_amdgcn_mfma_f32_16x16x32_f16(a0, b, acc[0][nt], 0, 0, 0);
      acc[1][nt] = __builtin_amdgcn_mfma_f32_16x16x32_f16(a1, b, acc[1][nt], 0, 0, 0);
    }
  }
  // epilogue: D-layout n = lane&15, m = (lane>>4)*4 + r ; row-major store
  const int nlo = lane & 15, mq = (lane >> 4) * 4;
#pragma unroll
  for (int mt = 0; mt < 2; ++mt)
#pragma unroll
    for (int nt = 0; nt < 13; ++nt)
#pragma unroll
      for (int r = 0; r < 4; ++r) {
        int row = m0 + wave * 32 + mt * 16 + mq + r;
        if (row < N_NODES)
          hpre[(size_t)row * HID2 + br * HIDP + nt * 16 + nlo] = (_Float16)acc[mt][nt][r];
      }
}

// ---------------- agg1: CSR gather-reduce (src-sorted sweep) + relu + W2 dot --------
// one wave per dst node; lane L owns 8 contiguous features of the 416-row.
// Edges are sorted by src-stripe within each row -> concurrent waves sweep
// hpre in ascending order, keeping a ~3 MB moving band L2-resident.
__global__ __launch_bounds__(64) void agg1_kernel(const int2* __restrict__ ssw,
    const int* __restrict__ bptr, const _Float16* __restrict__ hpre,
    const float* __restrict__ b1comb, const float* __restrict__ W2comb,
    float4v* __restrict__ qtab) {
  const int d = blockIdx.x;
  const int lane = threadIdx.x;
  const int e0 = bptr[d * NSTRIPE], e1 = bptr[d * NSTRIPE + NSTRIPE];
  float acc[8];
#pragma unroll
  for (int j = 0; j < 8; ++j) acc[j] = 0.f;
  if (lane < 52) {
    const _Float16* hp = hpre + lane * 8;
    int e = e0;
    for (; e + 3 < e1; e += 4) {
      int2 s0 = ssw[e], s1 = ssw[e + 1], s2 = ssw[e + 2], s3 = ssw[e + 3];
      half8 h0 = *(const half8*)(hp + (size_t)s0.x * HID2);
      half8 h1 = *(const half8*)(hp + (size_t)s1.x * HID2);
      half8 h2 = *(const half8*)(hp + (size_t)s2.x * HID2);
      half8 h3 = *(const half8*)(hp + (size_t)s3.x * HID2);
      float w0 = __int_as_float(s0.y), w1 = __int_as_float(s1.y);
      float w2 = __int_as_float(s2.y), w3 = __int_as_float(s3.y);
#pragma unroll
      for (int j = 0; j < 8; ++j)
        acc[j] += w0 * (float)h0[j] + w1 * (float)h1[j]
                + w2 * (float)h2[j] + w3 * (float)h3[j];
    }
    for (; e < e1; ++e) {
      int2 s0 = ssw[e];
      half8 h0 = *(const half8*)(hp + (size_t)s0.x * HID2);
      float w0 = __int_as_float(s0.y);
#pragma unroll
      for (int j = 0; j < 8; ++j) acc[j] += w0 * (float)h0[j];
    }
  }
  float p0 = 0.f, p1 = 0.f;
  if (lane < 52) {
#pragma unroll
    for (int j = 0; j < 8; ++j) {
      int col = lane * 8 + j;
      float h = fmaxf(acc[j] + b1comb[col], 0.f);   // h1 (never materialized)
      p0 += h * W2comb[2 * col + 0];
      p1 += h * W2comb[2 * col + 1];
    }
  }
  __shared__ float red0[64], red1[64];
  red0[lane] = p0; red1[lane] = p1;
  __syncthreads();
  if (lane == 0) {
    float q10 = 0, q11 = 0, q20 = 0, q21 = 0;
    for (int l = 0; l < 26; ++l)  { q10 += red0[l]; q11 += red1[l]; }   // branch a (cols 0..207)
    for (int l = 26; l < 52; ++l) { q20 += red0[l]; q21 += red1[l]; }   // branch b (cols 208..415)
    qtab[d] = (float4v){q10, q11, q20, q21};
  }
}

// ---------------- agg2: layer-2 segment_sum + softmax + vote ----------------
__global__ __launch_bounds__(256) void agg2_kernel(const int2* __restrict__ ssw,
    const int* __restrict__ bptr, const float4v* __restrict__ qtab,
    const float* __restrict__ b2a, const float* __restrict__ b2b,
    float* __restrict__ out) {
  const int d = blockIdx.x * 4 + (threadIdx.x >> 6);
  const int lane = threadIdx.x & 63;
  const int e0 = bptr[d * NSTRIPE], e1 = bptr[d * NSTRIPE + NSTRIPE];
  float a0 = 0.f, a1 = 0.f, a2 = 0.f, a3 = 0.f;
  for (int e = e0 + lane; e < e1; e += 64) {
    int2 sw = ssw[e];
    float w = __int_as_float(sw.y);
    float4v q = qtab[sw.x];
    a0 += w * q[0]; a1 += w * q[1]; a2 += w * q[2]; a3 += w * q[3];
  }
#pragma unroll
  for (int off = 32; off > 0; off >>= 1) {
    a0 += __shfl_xor(a0, off);
    a1 += __shfl_xor(a1, off);
    a2 += __shfl_xor(a2, off);
    a3 += __shfl_xor(a3, off);
  }
  if (lane == 0) {
    float za0 = a0 + b2a[0], za1 = a1 + b2a[1];
    float zb0 = a2 + b2b[0], zb1 = a3 + b2b[1];
    float m1 = fmaxf(za0, za1);
    float ea0 = __expf(za0 - m1), ea1 = __expf(za1 - m1);
    float p10 = ea0 / (ea0 + ea1), p11 = ea1 / (ea0 + ea1);
    float m2 = fmaxf(zb0, zb1);
    float eb0 = __expf(zb0 - m2), eb1 = __expf(zb1 - m2);
    float p20 = eb0 / (eb0 + eb1), p21 = eb1 / (eb0 + eb1);
    float v0 = fmaxf(p10, p20), v1 = fmaxf(p11, p21);
    float s = v0 + v1;
    out[d * 2 + 0] = v0 / s;
    out[d * 2 + 1] = v1 / s;
  }
}

extern "C" void kernel_launch(void* const* d_in, const int* in_sizes, int n_in,
                              void* d_out, int out_size, void* d_ws, size_t ws_size,
                              hipStream_t stream) {
  const float* x        = (const float*)d_in[0];
  const int*   edge_src = (const int*)d_in[1];
  const int*   edge_dst = (const int*)d_in[2];
  const float* edge_w   = (const float*)d_in[3];
  const float* W1a = (const float*)d_in[4];
  const float* b1a = (const float*)d_in[5];
  const float* W2a = (const float*)d_in[6];
  const float* b2a = (const float*)d_in[7];
  const float* W1b = (const float*)d_in[8];
  const float* b1b = (const float*)d_in[9];
  const float* W2b = (const float*)d_in[10];
  const float* b2b = (const float*)d_in[11];
  float* out = (float*)d_out;

  char* ws = (char*)d_ws;
  size_t off = 0;
  auto alloc = [&](size_t bytes) -> void* {
    void* p = ws + off;
    off = (off + bytes + 255) & ~(size_t)255;
    return p;
  };
  _Float16* Wht  = (_Float16*)alloc((size_t)2 * HIDP * KDIM * sizeof(_Float16)); // 639 KB
  float* b1comb  = (float*)alloc(HID2 * sizeof(float));
  float* W2comb  = (float*)alloc(HID2 * 2 * sizeof(float));
  int* bptr      = (int*)alloc((NKEYS + 1) * sizeof(int));                       // 3.2 MB
  int* cnt       = (int*)alloc(NKEYS * sizeof(int));                             // 3.2 MB
  int* cnt2      = (int*)alloc(NKEYS * sizeof(int));                             // 3.2 MB
  int* bsum      = (int*)alloc(L0B * sizeof(int));
  int* bsumB     = (int*)alloc(L1B * sizeof(int));
  int* boff2     = (int*)alloc(L1B * sizeof(int));
  int* boff1     = (int*)alloc(L0B * sizeof(int));
  int2* ssw      = (int2*)alloc((size_t)N_EDGES * sizeof(int2));                 // 12.8 MB
  float4v* qtab  = (float4v*)alloc((size_t)N_NODES * sizeof(float4v));           // 800 KB
  _Float16* hpre = (_Float16*)alloc((size_t)N_NODES * HID2 * sizeof(_Float16));  // 41.6 MB, row-major
  (void)ws_size; (void)in_sizes; (void)n_in; (void)out_size;

  (void)hipMemsetAsync(cnt,  0, NKEYS * sizeof(int), stream);
  (void)hipMemsetAsync(cnt2, 0, NKEYS * sizeof(int), stream);

  prep_kernel<<<dim3((2 * HIDP * KDIM + 255) / 256), dim3(256), 0, stream>>>(
      W1a, b1a, W2a, W1b, b1b, W2b, Wht, b1comb, W2comb);
  hist_kernel<<<dim3((N_EDGES + 255) / 256), dim3(256), 0, stream>>>(edge_src, edge_dst, cnt);
  scanA_kernel<<<dim3(L0B), dim3(256), 0, stream>>>(cnt, bsum);
  scanM1_kernel<<<dim3(L1B), dim3(256), 0, stream>>>(bsum, bsumB);
  scanTop_kernel<<<dim3(1), dim3(64), 0, stream>>>(bsumB, boff2, bptr);
  scanMid_kernel<<<dim3(L1B), dim3(256), 0, stream>>>(bsum, boff2, boff1);
  scanLow_kernel<<<dim3(L0B), dim3(256), 0, stream>>>(cnt, boff1, bptr);
  permute_kernel<<<dim3((N_EDGES + 255) / 256), dim3(256), 0, stream>>>(
      edge_src, edge_dst, edge_w, bptr, cnt2, ssw);
  gemm1_kernel<<<dim3((N_NODES + 127) / 128, 2), dim3(256), 0, stream>>>(x, Wht, hpre);
  agg1_kernel<<<dim3(N_NODES), dim3(64), 0, stream>>>(ssw, bptr, hpre, b1comb, W2comb, qtab);
  agg2_kernel<<<dim3(N_NODES / 4), dim3(256), 0, stream>>>(ssw, bptr, qtab, b2a, b2b, out);
}